// Round 3
// baseline (204.177 us; speedup 1.0000x reference)
//
#include <hip/hip_runtime.h>
#include <hip/hip_bf16.h>

// R3: I/O is FP32 (per the reference source); internal compute bf16 MFMA.
// Pipeline: gemm(x fp32 -> qkv bf16) -> fused flash attn (bf16) -> gemm(aout bf16 -> out fp32).
// ws: qkv [8192*1152] bf16 @0 ; aout [8192*384] bf16 after. 25.2 MB total.

typedef __attribute__((__ext_vector_type__(8))) __bf16 bf16x8;
typedef __attribute__((__ext_vector_type__(8))) unsigned short ushort8;
typedef __attribute__((__ext_vector_type__(4))) float f32x4;

#define NEG_BIG (-1.0e30f)

__device__ __forceinline__ f32x4 mfma_16x16x32(bf16x8 a, bf16x8 b, f32x4 c) {
    return __builtin_amdgcn_mfma_f32_16x16x32_bf16(a, b, c, 0, 0, 0);
}

__device__ __forceinline__ unsigned short f2bf(float f) {
    union { float f; unsigned int i; } x; x.f = f;
    unsigned int u = x.i;
    return (unsigned short)((u + 0x7fffu + ((u >> 16) & 1u)) >> 16);
}

// Load 8 consecutive elements as bf16 (converting if fp32).
__device__ __forceinline__ ushort8 load8_bf16(const float* p) {
    float4 a = *(const float4*)p;
    float4 b = *(const float4*)(p + 4);
    ushort8 r;
    r[0] = f2bf(a.x); r[1] = f2bf(a.y); r[2] = f2bf(a.z); r[3] = f2bf(a.w);
    r[4] = f2bf(b.x); r[5] = f2bf(b.y); r[6] = f2bf(b.z); r[7] = f2bf(b.w);
    return r;
}
__device__ __forceinline__ ushort8 load8_bf16(const unsigned short* p) {
    return *(const ushort8*)p;
}

// C[M,N] = A[M,K] @ B[N,K]^T + bias[N]; A is TA (fp32 or bf16-as-ushort), B/bias fp32,
// C is TC (fp32 or bf16-as-ushort). bf16 MFMA, fp32 accumulate.
// 128x128 tile, BK=32, 256 threads (4 waves as 2x2 of 64x64).
template <typename TA, typename TC>
__global__ __launch_bounds__(256) void gemm_bt_bias(
    const TA* __restrict__ A,
    const float* __restrict__ B,
    const float* __restrict__ bias,
    TC* __restrict__ C,
    int M, int N, int K)
{
    const int tid  = threadIdx.x;
    const int lane = tid & 63;
    const int wave = tid >> 6;
    const int l15  = lane & 15;
    const int quad = lane >> 4;
    const int m0 = blockIdx.x * 128;
    const int n0 = blockIdx.y * 128;
    const int wm = (wave >> 1) * 64;
    const int wn = (wave & 1) * 64;

    __shared__ __align__(16) unsigned short As[128 * 32];
    __shared__ __align__(16) unsigned short Bs[128 * 32];

    f32x4 acc[4][4];
    #pragma unroll
    for (int i = 0; i < 4; ++i)
        #pragma unroll
        for (int j = 0; j < 4; ++j)
            acc[i][j] = (f32x4){0.f, 0.f, 0.f, 0.f};

    for (int k0 = 0; k0 < K; k0 += 32) {
        // Stage 128x32 A and B tiles as 512 8-elem chunks each; 2 chunks/thread.
        // chunk i -> row i>>2, koff (i&3)*8, LDS elems i*8.. (row-major [128][32]).
        #pragma unroll
        for (int t = 0; t < 2; ++t) {
            int i = tid + t * 256;
            ushort8 va = load8_bf16(A + (size_t)(m0 + (i >> 2)) * K + k0 + (i & 3) * 8);
            ushort8 vb = load8_bf16(B + (size_t)(n0 + (i >> 2)) * K + k0 + (i & 3) * 8);
            *(ushort8*)(As + i * 8) = va;
            *(ushort8*)(Bs + i * 8) = vb;
        }
        __syncthreads();   // LDS tiles valid

        bf16x8 af[4], bff[4];
        #pragma unroll
        for (int mt = 0; mt < 4; ++mt)
            af[mt] = *(const bf16x8*)(As + (wm + mt * 16 + l15) * 32 + quad * 8);
        #pragma unroll
        for (int nt = 0; nt < 4; ++nt)
            bff[nt] = *(const bf16x8*)(Bs + (wn + nt * 16 + l15) * 32 + quad * 8);
        #pragma unroll
        for (int mt = 0; mt < 4; ++mt)
            #pragma unroll
            for (int nt = 0; nt < 4; ++nt)
                acc[mt][nt] = mfma_16x16x32(af[mt], bff[nt], acc[mt][nt]);
        __syncthreads();   // reads done before next stage overwrites
    }

    #pragma unroll
    for (int nt = 0; nt < 4; ++nt) {
        int n = n0 + wn + nt * 16 + l15;
        float bv = bias[n];
        #pragma unroll
        for (int mt = 0; mt < 4; ++mt) {
            int mbase = m0 + wm + mt * 16 + quad * 4;
            #pragma unroll
            for (int r = 0; r < 4; ++r) {
                float val = acc[mt][nt][r] + bv;
                if constexpr (sizeof(TC) == 2)
                    C[(size_t)(mbase + r) * N + n] = (TC)f2bf(val);
                else
                    C[(size_t)(mbase + r) * N + n] = (TC)val;
            }
        }
    }
}

// Fused attention over bf16 qkv scratch: one block per (q-tile 64, head, batch).
// qkv rows [8192][1152]: q at col h*64, k at 384+h*64, v at 768+h*64.
__global__ __launch_bounds__(256) void attn_fused(
    const unsigned short* __restrict__ qkv,
    unsigned short* __restrict__ aout)   // [8192][384] bf16
{
    const int tid  = threadIdx.x;
    const int wave = tid >> 6;
    const int lane = tid & 63;
    const int l15  = lane & 15;
    const int quad = lane >> 4;
    const int qt = blockIdx.x;   // 0..15
    const int h  = blockIdx.y;   // 0..5
    const int b  = blockIdx.z;   // 0..7

    const size_t rowbase = (size_t)b * 1024;
    const unsigned short* Qp = qkv + rowbase * 1152 + h * 64;
    const unsigned short* Kp = Qp + 384;
    const unsigned short* Vp = Qp + 768;
    const int q0 = qt * 64 + wave * 16;

    __shared__ __align__(16) unsigned short Vt[64 * 40];      // [d][kv], stride 40
    __shared__ __align__(16) unsigned short Ps[4][16 * 40];   // per-wave P scratch

    bf16x8 aq[2];
    {
        const unsigned short* qrow = Qp + (size_t)(q0 + l15) * 1152 + quad * 8;
        aq[0] = *(const bf16x8*)(qrow);
        aq[1] = *(const bf16x8*)(qrow + 32);
    }

    f32x4 accO[4];
    #pragma unroll
    for (int dt = 0; dt < 4; ++dt) accO[dt] = (f32x4){0.f, 0.f, 0.f, 0.f};
    float m_run[4], l_run[4];
    #pragma unroll
    for (int r = 0; r < 4; ++r) { m_run[r] = NEG_BIG; l_run[r] = 0.f; }

    for (int kv0 = 0; kv0 < 1024; kv0 += 32) {
        __syncthreads();   // previous Vt reads complete
        {   // stage V transposed
            int kv = tid >> 3;
            int d0 = (tid & 7) * 8;
            ushort8 v = *(const ushort8*)(Vp + (size_t)(kv0 + kv) * 1152 + d0);
            #pragma unroll
            for (int j = 0; j < 8; ++j)
                Vt[(d0 + j) * 40 + kv] = v[j];
        }
        __syncthreads();   // Vt valid

        f32x4 s[2];
        #pragma unroll
        for (int jt = 0; jt < 2; ++jt) {
            const unsigned short* krow = Kp + (size_t)(kv0 + jt * 16 + l15) * 1152 + quad * 8;
            bf16x8 bk0 = *(const bf16x8*)(krow);
            bf16x8 bk1 = *(const bf16x8*)(krow + 32);
            f32x4 z = (f32x4){0.f, 0.f, 0.f, 0.f};
            z = mfma_16x16x32(aq[0], bk0, z);
            z = mfma_16x16x32(aq[1], bk1, z);
            s[jt] = z;
        }

        #pragma unroll
        for (int r = 0; r < 4; ++r) {
            float s0 = s[0][r] * 0.125f;
            float s1 = s[1][r] * 0.125f;
            s0 = (s0 < 0.f) ? -10000.f : s0;   // ref's exact masked fill
            s1 = (s1 < 0.f) ? -10000.f : s1;
            float mx = fmaxf(s0, s1);
            #pragma unroll
            for (int off = 1; off < 16; off <<= 1)
                mx = fmaxf(mx, __shfl_xor(mx, off, 64));
            float mnew = fmaxf(m_run[r], mx);
            float alpha = __expf(m_run[r] - mnew);
            float p0 = __expf(s0 - mnew);
            float p1 = __expf(s1 - mnew);
            float ps = p0 + p1;
            #pragma unroll
            for (int off = 1; off < 16; off <<= 1)
                ps += __shfl_xor(ps, off, 64);
            l_run[r] = l_run[r] * alpha + ps;
            m_run[r] = mnew;
            #pragma unroll
            for (int dt = 0; dt < 4; ++dt) accO[dt][r] *= alpha;
            Ps[wave][(quad * 4 + r) * 40 + l15]      = f2bf(p0);
            Ps[wave][(quad * 4 + r) * 40 + 16 + l15] = f2bf(p1);
        }

        __threadfence_block();
        bf16x8 pf = *(const bf16x8*)(&Ps[wave][l15 * 40 + quad * 8]);
        #pragma unroll
        for (int dt = 0; dt < 4; ++dt) {
            bf16x8 vf = *(const bf16x8*)(&Vt[(dt * 16 + l15) * 40 + quad * 8]);
            accO[dt] = mfma_16x16x32(pf, vf, accO[dt]);
        }
    }

    #pragma unroll
    for (int dt = 0; dt < 4; ++dt) {
        #pragma unroll
        for (int r = 0; r < 4; ++r) {
            int m = q0 + quad * 4 + r;
            int col = h * 64 + dt * 16 + l15;
            aout[(rowbase + m) * 384 + col] = f2bf(accO[dt][r] / l_run[r]);
        }
    }
}

extern "C" void kernel_launch(void* const* d_in, const int* in_sizes, int n_in,
                              void* d_out, int out_size, void* d_ws, size_t ws_size,
                              hipStream_t stream) {
    const float* x      = (const float*)d_in[0];  // [8,1024,384] fp32
    const float* w_qkv  = (const float*)d_in[1];  // [1152,384] fp32
    const float* b_qkv  = (const float*)d_in[2];  // [1152] fp32
    const float* w_proj = (const float*)d_in[3];  // [384,384] fp32
    const float* b_proj = (const float*)d_in[4];  // [384] fp32
    float* out = (float*)d_out;                   // [8,1024,384] fp32

    unsigned short* qkv  = (unsigned short*)d_ws;           // 8192*1152 bf16
    unsigned short* aout = qkv + (size_t)8192 * 1152;       // 8192*384 bf16

    gemm_bt_bias<float, unsigned short>
        <<<dim3(64, 9), 256, 0, stream>>>(x, w_qkv, b_qkv, qkv, 8192, 1152, 384);
    attn_fused<<<dim3(16, 6, 8), 256, 0, stream>>>(qkv, aout);
    gemm_bt_bias<unsigned short, float>
        <<<dim3(64, 3), 256, 0, stream>>>(aout, w_proj, b_proj, out, 8192, 384, 384);
}

// Round 4
// 195.968 us; speedup vs baseline: 1.0419x; 1.0419x over previous
//
#include <hip/hip_runtime.h>
#include <hip/hip_bf16.h>

// R4: fp32 I/O, bf16 internal.
// cvt(x,wq,wp -> bf16) -> gemm<0>(qkv: qk bf16 [8192][768] q-prescaled, vT [48][64][1024])
//   -> attn (no barriers, no online-max, direct exp) -> gemm<1>(proj -> fp32 out).
// ws (ushort elems): qk 6291456 | vT 3145728 | aout 3145728 | xb 3145728 | wqb 442368 | wpb 147456
// total 32.8 MB.

typedef __attribute__((__ext_vector_type__(8))) __bf16 bf16x8;
typedef __attribute__((__ext_vector_type__(8))) unsigned short ushort8;
typedef __attribute__((__ext_vector_type__(4))) unsigned short ushort4v;
typedef __attribute__((__ext_vector_type__(4))) float f32x4;

#define NX 3145728   // 8192*384
#define NQ 442368    // 1152*384
#define NP 147456    // 384*384

__device__ __forceinline__ f32x4 mfma_16x16x32(bf16x8 a, bf16x8 b, f32x4 c) {
    return __builtin_amdgcn_mfma_f32_16x16x32_bf16(a, b, c, 0, 0, 0);
}

__device__ __forceinline__ unsigned short f2bf(float f) {
    union { float f; unsigned int i; } x; x.f = f;
    unsigned int u = x.i;
    return (unsigned short)((u + 0x7fffu + ((u >> 16) & 1u)) >> 16);
}

// fp32 -> bf16 for x, w_qkv, w_proj in one grid. 4 elems/thread.
__global__ __launch_bounds__(256) void cvt_bf16(
    const float* __restrict__ x, const float* __restrict__ wq, const float* __restrict__ wp,
    unsigned short* __restrict__ xb, unsigned short* __restrict__ wqb, unsigned short* __restrict__ wpb)
{
    int i = blockIdx.x * 256 + threadIdx.x;   // chunk of 4
    const float* src; unsigned short* dst; int off;
    if (i < NX / 4)              { src = x;  dst = xb;  off = i * 4; }
    else if (i < (NX + NQ) / 4)  { src = wq; dst = wqb; off = i * 4 - NX; }
    else                         { src = wp; dst = wpb; off = i * 4 - NX - NQ; }
    float4 v = *(const float4*)(src + off);
    ushort4v r;
    r[0] = f2bf(v.x); r[1] = f2bf(v.y); r[2] = f2bf(v.z); r[3] = f2bf(v.w);
    *(ushort4v*)(dst + off) = r;
}

// C = A[M,K] @ B[N,K]^T + bias. bf16 in, fp32 acc. 128x128 tile, BK=32, 4 waves,
// global_load_lds width=16 staging (m97 pattern).
// MODE 0 (QKV): n<384 -> qk (x0.125), n<768 -> qk, n>=768 -> vT transposed (packed ushort4).
// MODE 1 (proj): fp32 out + bias.
template <int MODE>
__global__ __launch_bounds__(256) void gemm_bt(
    const unsigned short* __restrict__ A,
    const unsigned short* __restrict__ B,
    const float* __restrict__ bias,
    unsigned short* __restrict__ qk,
    unsigned short* __restrict__ vT,
    float* __restrict__ out,
    int M, int N, int K)
{
    const int tid  = threadIdx.x;
    const int lane = tid & 63;
    const int wave = tid >> 6;
    const int l15  = lane & 15;
    const int quad = lane >> 4;
    const int m0 = blockIdx.x * 128;
    const int n0 = blockIdx.y * 128;
    const int wm = (wave >> 1) * 64;
    const int wn = (wave & 1) * 64;

    __shared__ __align__(16) unsigned short As[128 * 32];
    __shared__ __align__(16) unsigned short Bs[128 * 32];

    f32x4 acc[4][4];
    #pragma unroll
    for (int i = 0; i < 4; ++i)
        #pragma unroll
        for (int j = 0; j < 4; ++j)
            acc[i][j] = (f32x4){0.f, 0.f, 0.f, 0.f};

    for (int k0 = 0; k0 < K; k0 += 32) {
        // 512 chunks of 16B per tile; chunk i -> row i>>2, koff (i&3)*8, LDS bytes i*16.
        // DMA dest = wave-uniform base + lane*16B.
        #pragma unroll
        for (int t = 0; t < 2; ++t) {
            int i = tid + t * 256;
            const unsigned short* ga = A + (size_t)(m0 + (i >> 2)) * K + k0 + (i & 3) * 8;
            unsigned short* la = As + t * 2048 + wave * 512;
            __builtin_amdgcn_global_load_lds(
                (const __attribute__((address_space(1))) unsigned int*)ga,
                (__attribute__((address_space(3))) unsigned int*)la, 16, 0, 0);
            const unsigned short* gb = B + (size_t)(n0 + (i >> 2)) * K + k0 + (i & 3) * 8;
            unsigned short* lb = Bs + t * 2048 + wave * 512;
            __builtin_amdgcn_global_load_lds(
                (const __attribute__((address_space(1))) unsigned int*)gb,
                (__attribute__((address_space(3))) unsigned int*)lb, 16, 0, 0);
        }
        __syncthreads();   // drains vmcnt; tiles valid

        bf16x8 af[4], bff[4];
        #pragma unroll
        for (int mt = 0; mt < 4; ++mt)
            af[mt] = *(const bf16x8*)(As + (wm + mt * 16 + l15) * 32 + quad * 8);
        #pragma unroll
        for (int nt = 0; nt < 4; ++nt)
            bff[nt] = *(const bf16x8*)(Bs + (wn + nt * 16 + l15) * 32 + quad * 8);
        #pragma unroll
        for (int mt = 0; mt < 4; ++mt)
            #pragma unroll
            for (int nt = 0; nt < 4; ++nt)
                acc[mt][nt] = mfma_16x16x32(af[mt], bff[nt], acc[mt][nt]);
        __syncthreads();   // reads done before next stage overwrites
    }

    if constexpr (MODE == 0) {
        if (n0 < 768) {
            const float scale = (n0 < 384) ? 0.125f : 1.0f;   // region is 128-tile aligned
            #pragma unroll
            for (int nt = 0; nt < 4; ++nt) {
                int n = n0 + wn + nt * 16 + l15;
                float bv = bias[n];
                #pragma unroll
                for (int mt = 0; mt < 4; ++mt) {
                    int mbase = m0 + wm + mt * 16 + quad * 4;
                    #pragma unroll
                    for (int r = 0; r < 4; ++r)
                        qk[(size_t)(mbase + r) * 768 + n] = f2bf((acc[mt][nt][r] + bv) * scale);
                }
            }
        } else {
            #pragma unroll
            for (int nt = 0; nt < 4; ++nt) {
                int n = n0 + wn + nt * 16 + l15;
                float bv = bias[n];
                int h = (n - 768) >> 6;
                int d = (n - 768) & 63;
                #pragma unroll
                for (int mt = 0; mt < 4; ++mt) {
                    int mbase = m0 + wm + mt * 16 + quad * 4;
                    int bb = mbase >> 10;
                    int mm = mbase & 1023;
                    ushort4v pk;
                    #pragma unroll
                    for (int r = 0; r < 4; ++r) pk[r] = f2bf(acc[mt][nt][r] + bv);
                    *(ushort4v*)(vT + ((size_t)((bb * 6 + h) * 64 + d) << 10) + mm) = pk;
                }
            }
        }
    } else {
        #pragma unroll
        for (int nt = 0; nt < 4; ++nt) {
            int n = n0 + wn + nt * 16 + l15;
            float bv = bias[n];
            #pragma unroll
            for (int mt = 0; mt < 4; ++mt) {
                int mbase = m0 + wm + mt * 16 + quad * 4;
                #pragma unroll
                for (int r = 0; r < 4; ++r)
                    out[(size_t)(mbase + r) * N + n] = acc[mt][nt][r] + bv;
            }
        }
    }
}

// Fused attention, no block-level sync. Block = (q-tile 64, head, batch), 4 waves x 16 q-rows.
// qk [8192][768]: q (pre-scaled by 0.125) at h*64, k at 384+h*64. vT [48][64][1024].
// Threshold mask at 0: p = s<0 ? 0 : exp(s); plain sum (no max-sub needed: s <= ~8).
__global__ __launch_bounds__(256) void attn_fused(
    const unsigned short* __restrict__ qk,
    const unsigned short* __restrict__ vT,
    unsigned short* __restrict__ aout)   // [8192][384] bf16
{
    const int tid  = threadIdx.x;
    const int wave = tid >> 6;
    const int lane = tid & 63;
    const int l15  = lane & 15;
    const int quad = lane >> 4;
    const int qt = blockIdx.x;   // 0..15
    const int h  = blockIdx.y;   // 0..5
    const int b  = blockIdx.z;   // 0..7

    const size_t rowbase = (size_t)b * 1024;
    const unsigned short* Qp  = qk + rowbase * 768 + h * 64;
    const unsigned short* Kp  = Qp + 384;
    const unsigned short* VTh = vT + ((size_t)(b * 6 + h) << 16);   // 64*1024
    const int q0 = qt * 64 + wave * 16;

    __shared__ __align__(16) unsigned short Ps[4][16 * 40];   // per-wave P scratch

    bf16x8 aq[2];
    {
        const unsigned short* qrow = Qp + (size_t)(q0 + l15) * 768 + quad * 8;
        aq[0] = *(const bf16x8*)(qrow);
        aq[1] = *(const bf16x8*)(qrow + 32);
    }

    f32x4 accO[4];
    #pragma unroll
    for (int dt = 0; dt < 4; ++dt) accO[dt] = (f32x4){0.f, 0.f, 0.f, 0.f};
    float lsum[4] = {0.f, 0.f, 0.f, 0.f};

    for (int kv0 = 0; kv0 < 1024; kv0 += 32) {
        f32x4 s[2];
        #pragma unroll
        for (int jt = 0; jt < 2; ++jt) {
            const unsigned short* krow = Kp + (size_t)(kv0 + jt * 16 + l15) * 768 + quad * 8;
            bf16x8 bk0 = *(const bf16x8*)(krow);
            bf16x8 bk1 = *(const bf16x8*)(krow + 32);
            f32x4 z = (f32x4){0.f, 0.f, 0.f, 0.f};
            z = mfma_16x16x32(aq[0], bk0, z);
            z = mfma_16x16x32(aq[1], bk1, z);
            s[jt] = z;
        }

        #pragma unroll
        for (int r = 0; r < 4; ++r) {
            float s0 = s[0][r];
            float s1 = s[1][r];
            float p0 = (s0 < 0.f) ? 0.f : __expf(s0);   // masked -> exact 0, matches ref
            float p1 = (s1 < 0.f) ? 0.f : __expf(s1);
            lsum[r] += p0 + p1;
            Ps[wave][(quad * 4 + r) * 40 + l15]      = f2bf(p0);
            Ps[wave][(quad * 4 + r) * 40 + 16 + l15] = f2bf(p1);
        }

        __threadfence_block();   // order Ps writes before re-read (per-wave data)
        bf16x8 pf = *(const bf16x8*)(&Ps[wave][l15 * 40 + quad * 8]);
        #pragma unroll
        for (int dt = 0; dt < 4; ++dt) {
            bf16x8 vf = *(const bf16x8*)(VTh + (size_t)(dt * 16 + l15) * 1024 + kv0 + quad * 8);
            accO[dt] = mfma_16x16x32(pf, vf, accO[dt]);
        }
    }

    // Row sums: reduce per-lane partials across the 16 lanes of each C-row group.
    #pragma unroll
    for (int r = 0; r < 4; ++r) {
        float v = lsum[r];
        #pragma unroll
        for (int off = 1; off < 16; off <<= 1)
            v += __shfl_xor(v, off, 64);
        lsum[r] = v;
    }

    #pragma unroll
    for (int dt = 0; dt < 4; ++dt) {
        #pragma unroll
        for (int r = 0; r < 4; ++r) {
            int m = q0 + quad * 4 + r;
            int col = h * 64 + dt * 16 + l15;
            aout[(rowbase + m) * 384 + col] = f2bf(accO[dt][r] / lsum[r]);
        }
    }
}

extern "C" void kernel_launch(void* const* d_in, const int* in_sizes, int n_in,
                              void* d_out, int out_size, void* d_ws, size_t ws_size,
                              hipStream_t stream) {
    const float* x      = (const float*)d_in[0];  // [8,1024,384]
    const float* w_qkv  = (const float*)d_in[1];  // [1152,384]
    const float* b_qkv  = (const float*)d_in[2];  // [1152]
    const float* w_proj = (const float*)d_in[3];  // [384,384]
    const float* b_proj = (const float*)d_in[4];  // [384]
    float* out = (float*)d_out;                   // [8,1024,384]

    unsigned short* qk   = (unsigned short*)d_ws;        // 8192*768
    unsigned short* vT   = qk   + (size_t)8192 * 768;    // 48*64*1024
    unsigned short* aout = vT   + (size_t)48 * 64 * 1024;// 8192*384
    unsigned short* xb   = aout + (size_t)8192 * 384;    // 8192*384
    unsigned short* wqb  = xb   + (size_t)8192 * 384;    // 1152*384
    unsigned short* wpb  = wqb  + (size_t)1152 * 384;    // 384*384

    cvt_bf16<<<3648, 256, 0, stream>>>(x, w_qkv, w_proj, xb, wqb, wpb);
    gemm_bt<0><<<dim3(64, 9), 256, 0, stream>>>(xb, wqb, b_qkv, qk, vT, nullptr, 8192, 1152, 384);
    attn_fused<<<dim3(16, 6, 8), 256, 0, stream>>>(qk, vT, aout);
    gemm_bt<1><<<dim3(64, 3), 256, 0, stream>>>(aout, wpb, b_proj, nullptr, nullptr, out, 8192, 384, 384);
}